// Round 4
// baseline (1173.140 us; speedup 1.0000x reference)
//
#include <hip/hip_runtime.h>
#include <hip/hip_bf16.h>
#include <math.h>
#include <stdint.h>

#define N_NODES 100000
#define N_EDGES 1600000
#define IN_DIM 256
#define OUT_DIM 64

#define BSHIFT 7
#define BWIN   128                      // nodes per bucket window
#define NBUCK  782                      // ceil(100000 / 128)

typedef __attribute__((address_space(1))) const void GV;
typedef __attribute__((address_space(3))) void LV;

// ---------------------------------------------------------------------------
// Kernel A: W_h = h @ W.T  (100000x256 @ 256x64) + p_src/p_dst epilogue.
// (unchanged from round 3 — register-tiled, global_load_lds staging)
// ---------------------------------------------------------------------------
__global__ __launch_bounds__(256, 4) void gat_gemm(
    const float* __restrict__ h, const float* __restrict__ W,
    const float* __restrict__ a, float* __restrict__ Wh,
    float* __restrict__ p_src, float* __restrict__ p_dst)
{
    __shared__ char smem[40960];

    const int t = threadIdx.x;
    const int lane = t & 63;
    const int wv = t >> 6;
    const int ng = t & 15;
    const int cg = t >> 4;
    const int node0 = blockIdx.x * 64;

    const int chunk0 = wv * 2;
    const int r0 = chunk0 * 8 + (lane >> 3);
    const int r1 = r0 + 8;
    const int ks0 = (lane & 7) ^ (r0 & 7);
    const int ks1 = (lane & 7) ^ (r1 & 7);
    const int hrow0 = (node0 + r0 < N_NODES) ? node0 + r0 : N_NODES - 1;
    const int hrow1 = (node0 + r1 < N_NODES) ? node0 + r1 : N_NODES - 1;

    int hbase[4], wbase[4], wxor[4];
    #pragma unroll
    for (int i = 0; i < 4; ++i) hbase[i] = (ng + 16 * i) * 128;
    const int hxor = (ng & 7) << 4;
    #pragma unroll
    for (int j = 0; j < 4; ++j) {
        wbase[j] = (4 * cg + j) * 128;
        wxor[j] = ((4 * cg + j) & 7) << 4;
    }

    float acc[4][4];
    #pragma unroll
    for (int i = 0; i < 4; ++i)
        #pragma unroll
        for (int j = 0; j < 4; ++j) acc[i][j] = 0.f;

    #define STAGE(b, kc)                                                        \
    {                                                                           \
        char* hb = smem + (b) * 16384;                                          \
        char* wb = hb + 8192;                                                   \
        __builtin_amdgcn_global_load_lds(                                       \
            (GV*)(h + (size_t)hrow0 * IN_DIM + (kc) + ks0 * 4),                 \
            (LV*)(hb + chunk0 * 1024), 16, 0, 0);                               \
        __builtin_amdgcn_global_load_lds(                                       \
            (GV*)(h + (size_t)hrow1 * IN_DIM + (kc) + ks1 * 4),                 \
            (LV*)(hb + chunk0 * 1024 + 1024), 16, 0, 0);                        \
        __builtin_amdgcn_global_load_lds(                                       \
            (GV*)(W + (size_t)r0 * IN_DIM + (kc) + ks0 * 4),                    \
            (LV*)(wb + chunk0 * 1024), 16, 0, 0);                               \
        __builtin_amdgcn_global_load_lds(                                       \
            (GV*)(W + (size_t)r1 * IN_DIM + (kc) + ks1 * 4),                    \
            (LV*)(wb + chunk0 * 1024 + 1024), 16, 0, 0);                        \
    }

    STAGE(0, 0);
    asm volatile("s_waitcnt vmcnt(0)");
    __syncthreads();

    int cur = 0;
    #pragma unroll
    for (int kt = 0; kt < 8; ++kt) {
        if (kt < 7) STAGE(cur ^ 1, (kt + 1) * 32);

        const char* hb = smem + cur * 16384;
        const char* wb = hb + 8192;
        #pragma unroll
        for (int kk4 = 0; kk4 < 8; ++kk4) {
            float4 hv[4], wvv[4];
            #pragma unroll
            for (int i = 0; i < 4; ++i)
                hv[i] = *(const float4*)(hb + hbase[i] + (((kk4 << 4) ^ hxor)));
            #pragma unroll
            for (int j = 0; j < 4; ++j)
                wvv[j] = *(const float4*)(wb + wbase[j] + (((kk4 << 4) ^ wxor[j])));
            #pragma unroll
            for (int i = 0; i < 4; ++i)
                #pragma unroll
                for (int j = 0; j < 4; ++j) {
                    acc[i][j] = fmaf(hv[i].x, wvv[j].x, acc[i][j]);
                    acc[i][j] = fmaf(hv[i].y, wvv[j].y, acc[i][j]);
                    acc[i][j] = fmaf(hv[i].z, wvv[j].z, acc[i][j]);
                    acc[i][j] = fmaf(hv[i].w, wvv[j].w, acc[i][j]);
                }
        }

        if (kt < 7) asm volatile("s_waitcnt vmcnt(0)");
        __syncthreads();
        cur ^= 1;
    }
    #undef STAGE

    #pragma unroll
    for (int i = 0; i < 4; ++i) {
        const int n = node0 + ng + 16 * i;
        if (n < N_NODES) {
            float4 v = make_float4(acc[i][0], acc[i][1], acc[i][2], acc[i][3]);
            *(float4*)(Wh + (size_t)n * OUT_DIM + 4 * cg) = v;
        }
    }

    const float4 as = *(const float4*)(a + 4 * cg);
    const float4 ad = *(const float4*)(a + OUT_DIM + 4 * cg);
    float* pp = (float*)(smem + 32768);
    #pragma unroll
    for (int i = 0; i < 4; ++i) {
        const int nl = ng + 16 * i;
        pp[cg * 64 + nl] =
            acc[i][0] * as.x + acc[i][1] * as.y + acc[i][2] * as.z + acc[i][3] * as.w;
        pp[1024 + cg * 64 + nl] =
            acc[i][0] * ad.x + acc[i][1] * ad.y + acc[i][2] * ad.z + acc[i][3] * ad.w;
    }
    __syncthreads();
    if (t < 128) {
        const int which = t >> 6, nl = t & 63;
        float s = 0.f;
        #pragma unroll
        for (int c = 0; c < 16; ++c) s += pp[which * 1024 + c * 64 + nl];
        if (node0 + nl < N_NODES) {
            if (which) p_dst[node0 + nl] = s;
            else       p_src[node0 + nl] = s;
        }
    }
}

// ---------------------------------------------------------------------------
// Coarse histogram over 782 dst-buckets (LDS-combined -> few global atomics)
// ---------------------------------------------------------------------------
__global__ __launch_bounds__(256) void gat_coarse_hist(
    const int* __restrict__ dst, int* __restrict__ bcnt)
{
    __shared__ int lh[NBUCK];
    for (int i = threadIdx.x; i < NBUCK; i += 256) lh[i] = 0;
    __syncthreads();
    for (int e = blockIdx.x * 256 + threadIdx.x; e < N_EDGES; e += gridDim.x * 256)
        atomicAdd(&lh[dst[e] >> BSHIFT], 1);
    __syncthreads();
    for (int i = threadIdx.x; i < NBUCK; i += 256) {
        const int v = lh[i];
        if (v) atomicAdd(&bcnt[i], v);
    }
}

// ---------------------------------------------------------------------------
// 1-block exclusive scan of bucket counts -> bucket_base + cursor init
// ---------------------------------------------------------------------------
__global__ __launch_bounds__(1024) void gat_coarse_scan(
    const int* __restrict__ bcnt, int* __restrict__ bucket_base,
    int* __restrict__ bcursor)
{
    __shared__ int tmp[1024];
    const int t = threadIdx.x;
    const int v = (t < NBUCK) ? bcnt[t] : 0;
    tmp[t] = v;
    __syncthreads();
    int val = v;
    for (int s = 1; s < 1024; s <<= 1) {
        const int add = (t >= s) ? tmp[t - s] : 0;
        __syncthreads();
        val += add;
        tmp[t] = val;
        __syncthreads();
    }
    if (t < NBUCK) {
        const int excl = val - v;
        bucket_base[t] = excl;
        bcursor[t] = excl;
    }
    if (t == 0) bucket_base[NBUCK] = N_EDGES;
}

// ---------------------------------------------------------------------------
// Bucket scatter: edge -> (src | local_node<<17, bits(e_val)) at cursor++.
// Writes are quasi-sequential per bucket (782 hot frontier lines).
// ---------------------------------------------------------------------------
__global__ __launch_bounds__(256) void gat_bucket_scatter(
    const int* __restrict__ src, const int* __restrict__ dst,
    const float* __restrict__ p_src, const float* __restrict__ p_dst,
    int* __restrict__ bcursor, int2* __restrict__ ebuf)
{
    const int e = blockIdx.x * 256 + threadIdx.x;   // grid covers exactly N_EDGES
    const int se = src[e], de = dst[e];
    const float ev = fmaxf(p_src[se] + p_dst[de], 0.f);
    const int b = de >> BSHIFT;
    const int pos = atomicAdd(&bcursor[b], 1);
    ebuf[pos] = make_int2(se | ((de & (BWIN - 1)) << 17), __float_as_int(ev));
}

// ---------------------------------------------------------------------------
// Bucket aggregate: one block per bucket (128-node window).
// LDS: pacc[128][64] (32KB) + m[128] + s[128]. Phases:
//   1. per-node max via LDS atomicMax on non-negative float bits
//   2+3. wave per edge: ex=exp(ev-m); s += ex (lane0); pacc[ln][lane] += ex*Wh
//   4. out = pacc / s  (coalesced 32KB store)
// No global atomics, no fine CSR.
// ---------------------------------------------------------------------------
__global__ __launch_bounds__(256, 4) void gat_bucket_agg(
    const int2* __restrict__ ebuf, const int* __restrict__ bucket_base,
    const float* __restrict__ Wh, float* __restrict__ out)
{
    __shared__ float pacc[BWIN * OUT_DIM];   // 32 KB
    __shared__ float mval[BWIN];
    __shared__ float sval[BWIN];

    const int t = threadIdx.x;
    const int b = blockIdx.x;
    const int eb0 = __builtin_amdgcn_readfirstlane(bucket_base[b]);
    const int eb1 = __builtin_amdgcn_readfirstlane(bucket_base[b + 1]);
    const int node_base = b << BSHIFT;

    for (int i = t; i < BWIN * OUT_DIM; i += 256) pacc[i] = 0.f;
    if (t < BWIN) { mval[t] = 0.f; sval[t] = 0.f; }
    __syncthreads();

    // phase 1: per-node segment max (e >= 0 so int-bit max == float max)
    for (int k = eb0 + t; k < eb1; k += 256) {
        const int2 e = ebuf[k];
        atomicMax((int*)&mval[e.x >> 17], e.y);
    }
    __syncthreads();

    // phase 2+3: wave per edge, 4-deep ILP on the Wh gather
    const int lane = t & 63;
    const int wv = t >> 6;
    for (int k0 = eb0 + wv * 4; k0 < eb1; k0 += 16) {
        int2 e[4];
        float w[4];
        #pragma unroll
        for (int j = 0; j < 4; ++j)
            if (k0 + j < eb1) e[j] = ebuf[k0 + j];
        #pragma unroll
        for (int j = 0; j < 4; ++j)
            if (k0 + j < eb1)
                w[j] = Wh[(size_t)(e[j].x & 0x1FFFF) * OUT_DIM + lane];
        #pragma unroll
        for (int j = 0; j < 4; ++j)
            if (k0 + j < eb1) {
                const int ln = e[j].x >> 17;
                const float ex = __expf(__int_as_float(e[j].y) - mval[ln]);
                if (lane == 0) atomicAdd(&sval[ln], ex);
                atomicAdd(&pacc[(ln << 6) + lane], ex * w[j]);
            }
    }
    __syncthreads();

    // phase 4: coalesced store
    for (int i = t; i < BWIN * OUT_DIM; i += 256) {
        const int ln = i >> 6;
        const int node = node_base + ln;
        if (node < N_NODES) {
            const float s = sval[ln];
            out[(size_t)node * OUT_DIM + (i & 63)] = (s > 0.f) ? pacc[i] / s : 0.f;
        }
    }
}

// ---------------------------------------------------------------------------
extern "C" void kernel_launch(void* const* d_in, const int* in_sizes, int n_in,
                              void* d_out, int out_size, void* d_ws, size_t ws_size,
                              hipStream_t stream)
{
    const float* h  = (const float*)d_in[0];
    const int* src  = (const int*)d_in[1];
    const int* dst  = (const int*)d_in[2];
    const float* W  = (const float*)d_in[3];
    const float* a  = (const float*)d_in[4];
    float* out = (float*)d_out;

    // workspace layout (bytes), total ~39.2 MB
    char* ws = (char*)d_ws;
    float* Wh          = (float*)(ws);                 // 25,600,000
    float* p_src       = (float*)(ws + 25600000);      //    400,000
    float* p_dst       = (float*)(ws + 26000000);      //    400,000
    int*   bucket_base = (int*)  (ws + 26400000);      //      3,132 (NBUCK+1)
    int*   bcnt        = (int*)  (ws + 26403136);      //      3,128
    int*   bcursor     = (int*)  (ws + 26406264);      //      3,128
    int2*  ebuf        = (int2*) (ws + 26409392);      // 12,800,000

    hipMemsetAsync(bcnt, 0, NBUCK * sizeof(int), stream);

    gat_gemm<<<(N_NODES + 63) / 64, 256, 0, stream>>>(h, W, a, Wh, p_src, p_dst);

    gat_coarse_hist<<<256, 256, 0, stream>>>(dst, bcnt);
    gat_coarse_scan<<<1, 1024, 0, stream>>>(bcnt, bucket_base, bcursor);
    gat_bucket_scatter<<<N_EDGES / 256, 256, 0, stream>>>(src, dst, p_src, p_dst,
                                                          bcursor, ebuf);
    gat_bucket_agg<<<NBUCK, 256, 0, stream>>>(ebuf, bucket_base, Wh, out);
}

// Round 5
// 210.250 us; speedup vs baseline: 5.5797x; 5.5797x over previous
//
#include <hip/hip_runtime.h>
#include <hip/hip_bf16.h>
#include <math.h>
#include <stdint.h>

#define N_NODES 100000
#define N_EDGES 1600000
#define IN_DIM 256
#define OUT_DIM 64

#define NBUCK 6250                       // dst >> 4 ; 6250 * 16 = 100000 exact
#define NPART 128                        // edge partitions; 128 * 12500 = 1.6M exact
#define EPP   (N_EDGES / NPART)          // 12500 edges per partition
#define SCAN_N (NBUCK * NPART)           // 800000
#define SCAN_BLK ((SCAN_N + 4095) / 4096) // 196
#define MAXB 768                         // max edges/bucket (mean 256, sigma 16)

typedef __attribute__((address_space(1))) const void GV;
typedef __attribute__((address_space(3))) void LV;

// ---------------------------------------------------------------------------
// Kernel A: W_h = h @ W.T + p_src/p_dst epilogue (unchanged from R3).
// ---------------------------------------------------------------------------
__global__ __launch_bounds__(256, 4) void gat_gemm(
    const float* __restrict__ h, const float* __restrict__ W,
    const float* __restrict__ a, float* __restrict__ Wh,
    float* __restrict__ p_src, float* __restrict__ p_dst)
{
    __shared__ char smem[40960];

    const int t = threadIdx.x;
    const int lane = t & 63;
    const int wv = t >> 6;
    const int ng = t & 15;
    const int cg = t >> 4;
    const int node0 = blockIdx.x * 64;

    const int chunk0 = wv * 2;
    const int r0 = chunk0 * 8 + (lane >> 3);
    const int r1 = r0 + 8;
    const int ks0 = (lane & 7) ^ (r0 & 7);
    const int ks1 = (lane & 7) ^ (r1 & 7);
    const int hrow0 = (node0 + r0 < N_NODES) ? node0 + r0 : N_NODES - 1;
    const int hrow1 = (node0 + r1 < N_NODES) ? node0 + r1 : N_NODES - 1;

    int hbase[4], wbase[4], wxor[4];
    #pragma unroll
    for (int i = 0; i < 4; ++i) hbase[i] = (ng + 16 * i) * 128;
    const int hxor = (ng & 7) << 4;
    #pragma unroll
    for (int j = 0; j < 4; ++j) {
        wbase[j] = (4 * cg + j) * 128;
        wxor[j] = ((4 * cg + j) & 7) << 4;
    }

    float acc[4][4];
    #pragma unroll
    for (int i = 0; i < 4; ++i)
        #pragma unroll
        for (int j = 0; j < 4; ++j) acc[i][j] = 0.f;

    #define STAGE(b, kc)                                                        \
    {                                                                           \
        char* hb = smem + (b) * 16384;                                          \
        char* wb = hb + 8192;                                                   \
        __builtin_amdgcn_global_load_lds(                                       \
            (GV*)(h + (size_t)hrow0 * IN_DIM + (kc) + ks0 * 4),                 \
            (LV*)(hb + chunk0 * 1024), 16, 0, 0);                               \
        __builtin_amdgcn_global_load_lds(                                       \
            (GV*)(h + (size_t)hrow1 * IN_DIM + (kc) + ks1 * 4),                 \
            (LV*)(hb + chunk0 * 1024 + 1024), 16, 0, 0);                        \
        __builtin_amdgcn_global_load_lds(                                       \
            (GV*)(W + (size_t)r0 * IN_DIM + (kc) + ks0 * 4),                    \
            (LV*)(wb + chunk0 * 1024), 16, 0, 0);                               \
        __builtin_amdgcn_global_load_lds(                                       \
            (GV*)(W + (size_t)r1 * IN_DIM + (kc) + ks1 * 4),                    \
            (LV*)(wb + chunk0 * 1024 + 1024), 16, 0, 0);                        \
    }

    STAGE(0, 0);
    asm volatile("s_waitcnt vmcnt(0)");
    __syncthreads();

    int cur = 0;
    #pragma unroll
    for (int kt = 0; kt < 8; ++kt) {
        if (kt < 7) STAGE(cur ^ 1, (kt + 1) * 32);

        const char* hb = smem + cur * 16384;
        const char* wb = hb + 8192;
        #pragma unroll
        for (int kk4 = 0; kk4 < 8; ++kk4) {
            float4 hv[4], wvv[4];
            #pragma unroll
            for (int i = 0; i < 4; ++i)
                hv[i] = *(const float4*)(hb + hbase[i] + (((kk4 << 4) ^ hxor)));
            #pragma unroll
            for (int j = 0; j < 4; ++j)
                wvv[j] = *(const float4*)(wb + wbase[j] + (((kk4 << 4) ^ wxor[j])));
            #pragma unroll
            for (int i = 0; i < 4; ++i)
                #pragma unroll
                for (int j = 0; j < 4; ++j) {
                    acc[i][j] = fmaf(hv[i].x, wvv[j].x, acc[i][j]);
                    acc[i][j] = fmaf(hv[i].y, wvv[j].y, acc[i][j]);
                    acc[i][j] = fmaf(hv[i].z, wvv[j].z, acc[i][j]);
                    acc[i][j] = fmaf(hv[i].w, wvv[j].w, acc[i][j]);
                }
        }

        if (kt < 7) asm volatile("s_waitcnt vmcnt(0)");
        __syncthreads();
        cur ^= 1;
    }
    #undef STAGE

    #pragma unroll
    for (int i = 0; i < 4; ++i) {
        const int n = node0 + ng + 16 * i;
        if (n < N_NODES) {
            float4 v = make_float4(acc[i][0], acc[i][1], acc[i][2], acc[i][3]);
            *(float4*)(Wh + (size_t)n * OUT_DIM + 4 * cg) = v;
        }
    }

    const float4 as = *(const float4*)(a + 4 * cg);
    const float4 ad = *(const float4*)(a + OUT_DIM + 4 * cg);
    float* pp = (float*)(smem + 32768);
    #pragma unroll
    for (int i = 0; i < 4; ++i) {
        const int nl = ng + 16 * i;
        pp[cg * 64 + nl] =
            acc[i][0] * as.x + acc[i][1] * as.y + acc[i][2] * as.z + acc[i][3] * as.w;
        pp[1024 + cg * 64 + nl] =
            acc[i][0] * ad.x + acc[i][1] * ad.y + acc[i][2] * ad.z + acc[i][3] * ad.w;
    }
    __syncthreads();
    if (t < 128) {
        const int which = t >> 6, nl = t & 63;
        float s = 0.f;
        #pragma unroll
        for (int c = 0; c < 16; ++c) s += pp[which * 1024 + c * 64 + nl];
        if (node0 + nl < N_NODES) {
            if (which) p_dst[node0 + nl] = s;
            else       p_src[node0 + nl] = s;
        }
    }
}

// ---------------------------------------------------------------------------
// 2D histogram: cnt[bucket][partition], LDS-combined, NO global atomics.
// ---------------------------------------------------------------------------
__global__ __launch_bounds__(256) void gat_hist2d(
    const int* __restrict__ dst, int* __restrict__ cur2d)
{
    __shared__ int lh[NBUCK];
    for (int i = threadIdx.x; i < NBUCK; i += 256) lh[i] = 0;
    __syncthreads();
    const int e0 = blockIdx.x * EPP;
    for (int e = e0 + threadIdx.x; e < e0 + EPP; e += 256)
        atomicAdd(&lh[dst[e] >> 4], 1);
    __syncthreads();
    for (int i = threadIdx.x; i < NBUCK; i += 256)
        cur2d[i * NPART + blockIdx.x] = lh[i];
}

// ---------------------------------------------------------------------------
// 3-phase exclusive scan over cur2d[800000], in place.
// ---------------------------------------------------------------------------
__global__ __launch_bounds__(1024) void gat_scan1(int* __restrict__ data,
                                                  int* __restrict__ bsum)
{
    __shared__ int ts[1024];
    const int base = blockIdx.x * 4096 + threadIdx.x * 4;
    int v[4];
    #pragma unroll
    for (int j = 0; j < 4; ++j) {
        const int i = base + j;
        v[j] = (i < SCAN_N) ? data[i] : 0;
    }
    const int tsum = v[0] + v[1] + v[2] + v[3];
    ts[threadIdx.x] = tsum;
    __syncthreads();
    int val = tsum;
    for (int s = 1; s < 1024; s <<= 1) {
        const int add = (threadIdx.x >= s) ? ts[threadIdx.x - s] : 0;
        __syncthreads();
        val += add;
        ts[threadIdx.x] = val;
        __syncthreads();
    }
    int run = val - tsum;               // exclusive base of this thread
    #pragma unroll
    for (int j = 0; j < 4; ++j) {
        const int i = base + j;
        if (i < SCAN_N) data[i] = run;
        run += v[j];
    }
    if (threadIdx.x == 1023) bsum[blockIdx.x] = val;
}

__global__ __launch_bounds__(256) void gat_scan2(int* __restrict__ bsum)
{
    __shared__ int tmp[256];
    const int t = threadIdx.x;
    const int v = (t < SCAN_BLK) ? bsum[t] : 0;
    tmp[t] = v;
    __syncthreads();
    int val = v;
    for (int s = 1; s < 256; s <<= 1) {
        const int add = (t >= s) ? tmp[t - s] : 0;
        __syncthreads();
        val += add;
        tmp[t] = val;
        __syncthreads();
    }
    if (t < SCAN_BLK) bsum[t] = val - v;
}

__global__ __launch_bounds__(1024) void gat_scan3(int* __restrict__ data,
                                                  const int* __restrict__ bsum)
{
    const int add = bsum[blockIdx.x];
    const int base = blockIdx.x * 4096 + threadIdx.x * 4;
    #pragma unroll
    for (int j = 0; j < 4; ++j) {
        const int i = base + j;
        if (i < SCAN_N) data[i] += add;
    }
}

// ---------------------------------------------------------------------------
// Scatter: each partition-block owns a pre-reserved slice per bucket
// (cur2d from the scan) -> LDS-private cursors, NO global atomics.
// ebuf entry: src | local_node<<17  (4 B/edge).
// ---------------------------------------------------------------------------
__global__ __launch_bounds__(256) void gat_bucket_scatter(
    const int* __restrict__ src, const int* __restrict__ dst,
    const int* __restrict__ cur2d, int* __restrict__ ebuf)
{
    __shared__ int lcur[NBUCK];
    for (int i = threadIdx.x; i < NBUCK; i += 256)
        lcur[i] = cur2d[i * NPART + blockIdx.x];
    __syncthreads();
    const int e0 = blockIdx.x * EPP;
    for (int e = e0 + threadIdx.x; e < e0 + EPP; e += 256) {
        const int se = src[e], de = dst[e];
        const int pos = atomicAdd(&lcur[de >> 4], 1);
        ebuf[pos] = se | ((de & 15) << 17);
    }
}

// ---------------------------------------------------------------------------
// Sort+aggregate: one block per bucket (16 nodes). Stage edges in LDS,
// build fine order in LDS (16-counter hist+scan+rank), then wave-per-node:
// shuffle-max, exp+sum (ev cached in LDS), ILP-4 coalesced Wh gather into
// registers, single coalesced store. No global atomics.
// ---------------------------------------------------------------------------
__global__ __launch_bounds__(256) void gat_sort_agg(
    const int* __restrict__ ebuf, const int* __restrict__ cur2d,
    const float* __restrict__ p_src, const float* __restrict__ p_dst,
    const float* __restrict__ Wh, float* __restrict__ out)
{
    __shared__ int   ledge[MAXB];
    __shared__ float lex[MAXB];
    __shared__ unsigned short sidx[MAXB];
    __shared__ int lhist[16], lbase[16], lrank[16];

    const int t = threadIdx.x;
    const int b = blockIdx.x;
    const int e0 = cur2d[b * NPART];
    const int e1 = (b < NBUCK - 1) ? cur2d[(b + 1) * NPART] : N_EDGES;
    const int cnt = min(e1 - e0, MAXB);

    if (t < 16) { lhist[t] = 0; lrank[t] = 0; }
    __syncthreads();

    for (int i = t; i < cnt; i += 256) {
        const int v = ebuf[e0 + i];
        ledge[i] = v;
        atomicAdd(&lhist[(v >> 17) & 15], 1);
    }
    __syncthreads();
    if (t == 0) {
        int run = 0;
        #pragma unroll
        for (int j = 0; j < 16; ++j) { lbase[j] = run; run += lhist[j]; }
    }
    __syncthreads();
    for (int i = t; i < cnt; i += 256) {
        const int ln = (ledge[i] >> 17) & 15;
        const int pos = lbase[ln] + atomicAdd(&lrank[ln], 1);
        sidx[pos] = (unsigned short)i;
    }
    __syncthreads();

    const int lane = t & 63;
    const int wv = t >> 6;
    #pragma unroll
    for (int rr = 0; rr < 4; ++rr) {
        const int ln = wv * 4 + rr;
        const int sb = lbase[ln];
        const int d  = lhist[ln];
        const int node = (b << 4) + ln;
        const float pd = p_dst[node];

        // pass A: ev = relu(p_src[src]+pd); cache in lex; wave max
        float mloc = -INFINITY;
        for (int k = lane; k < d; k += 64) {
            const int sv = ledge[sidx[sb + k]] & 0x1FFFF;
            const float ev = fmaxf(p_src[sv] + pd, 0.f);
            lex[sb + k] = ev;
            mloc = fmaxf(mloc, ev);
        }
        #pragma unroll
        for (int o = 32; o > 0; o >>= 1) mloc = fmaxf(mloc, __shfl_xor(mloc, o));

        // pass B: ex = exp(ev - m); overwrite lex; wave sum
        float ssum = 0.f;
        for (int k = lane; k < d; k += 64) {
            const float ex = __expf(lex[sb + k] - mloc);
            lex[sb + k] = ex;
            ssum += ex;
        }
        #pragma unroll
        for (int o = 32; o > 0; o >>= 1) ssum += __shfl_xor(ssum, o);
        const float inv = (d > 0) ? 1.f / ssum : 0.f;

        // pass C: acc[lane] = sum_k ex_k * Wh[src_k][lane], ILP 4
        float acc = 0.f;
        for (int k0 = 0; k0 < d; k0 += 4) {
            float wr[4], exb[4];
            #pragma unroll
            for (int j = 0; j < 4; ++j) {
                if (k0 + j < d) {
                    const int sv = ledge[sidx[sb + k0 + j]] & 0x1FFFF;
                    wr[j]  = Wh[(size_t)sv * OUT_DIM + lane];
                    exb[j] = lex[sb + k0 + j];
                } else { wr[j] = 0.f; exb[j] = 0.f; }
            }
            #pragma unroll
            for (int j = 0; j < 4; ++j) acc = fmaf(exb[j], wr[j], acc);
        }

        out[(size_t)node * OUT_DIM + lane] = acc * inv;
    }
}

// ---------------------------------------------------------------------------
extern "C" void kernel_launch(void* const* d_in, const int* in_sizes, int n_in,
                              void* d_out, int out_size, void* d_ws, size_t ws_size,
                              hipStream_t stream)
{
    const float* h  = (const float*)d_in[0];
    const int* src  = (const int*)d_in[1];
    const int* dst  = (const int*)d_in[2];
    const float* W  = (const float*)d_in[3];
    const float* a  = (const float*)d_in[4];
    float* out = (float*)d_out;

    // workspace layout (bytes), total ~36.0 MB; every buffer fully written
    char* ws = (char*)d_ws;
    float* Wh     = (float*)(ws);                    // 25,600,000
    float* p_src  = (float*)(ws + 25600000);         //    400,000
    float* p_dst  = (float*)(ws + 26000000);         //    400,000
    int*   cur2d  = (int*)  (ws + 26400000);         //  3,200,000 (6250*128)
    int*   bsum   = (int*)  (ws + 29600000);         //        784
    int*   ebuf   = (int*)  (ws + 29600784);         //  6,400,000

    gat_gemm<<<(N_NODES + 63) / 64, 256, 0, stream>>>(h, W, a, Wh, p_src, p_dst);

    gat_hist2d<<<NPART, 256, 0, stream>>>(dst, cur2d);
    gat_scan1<<<SCAN_BLK, 1024, 0, stream>>>(cur2d, bsum);
    gat_scan2<<<1, 256, 0, stream>>>(bsum);
    gat_scan3<<<SCAN_BLK, 1024, 0, stream>>>(cur2d, bsum);
    gat_bucket_scatter<<<NPART, 256, 0, stream>>>(src, dst, cur2d, ebuf);

    gat_sort_agg<<<NBUCK, 256, 0, stream>>>(ebuf, cur2d, p_src, p_dst, Wh, out);
}